// Round 9
// baseline (86.297 us; speedup 1.0000x reference)
//
#include <hip/hip_runtime.h>
#include <hip/hip_bf16.h>

// Problem sizes (fixed by the reference)
#define S_LEN 256     // sequence length (t)
#define DM    512     // d_model (k / d)
#define DR    512     // d_rnn (s)
#define SEC   16      // t-steps per register section
#define NSEC  (S_LEN / SEC)   // 16 sections

typedef float f4 __attribute__((ext_vector_type(4)));
typedef float f2 __attribute__((ext_vector_type(2)));

// ws layout (floats):
//   xT  : [512][256]     at 0       (131072)
//   acT : f2[512][256]   at 131072  (262144)

__global__ __launch_bounds__(256) void k_transpose_x(const float* __restrict__ x,
                                                     float* __restrict__ xT) {
    __shared__ float tile[32][33];
    const int k0 = blockIdx.x * 32;
    const int t0 = blockIdx.y * 32;
    const int lx = threadIdx.x & 31;
    const int ly = threadIdx.x >> 5;
#pragma unroll
    for (int i = 0; i < 32; i += 8)
        tile[ly + i][lx] = x[(t0 + ly + i) * DM + k0 + lx];
    __syncthreads();
#pragma unroll
    for (int i = 0; i < 32; i += 8)
        xT[(k0 + ly + i) * S_LEN + t0 + lx] = tile[lx][ly + i];
}

// grid(128): block g -> GEMM rows {4g..4g+3, 512+4g..512+4g+3}; epilogue writes acT.
__global__ __launch_bounds__(256) void k_gemm_act(const float* __restrict__ xT,
                                                  const float* __restrict__ W1,
                                                  const float* __restrict__ b1,
                                                  const float* __restrict__ Lam,
                                                  f2* __restrict__ acT) {
    const int g  = blockIdx.x;       // 0..127
    const int t  = threadIdx.x;      // lane axis = t (coalesced xT loads)
    const int r0 = 4 * g;

    float ai[4] = {0.f, 0.f, 0.f, 0.f};
    float ar[4] = {0.f, 0.f, 0.f, 0.f};
    const float* __restrict__ xb = xT + t;

#pragma unroll 8
    for (int k = 0; k < DM; ++k) {
        const float xv = xb[k * S_LEN];
#pragma unroll
        for (int j = 0; j < 4; ++j) {
            ai[j] = fmaf(xv, W1[(r0 + j) * DM + k], ai[j]);        // wave-uniform
            ar[j] = fmaf(xv, W1[(512 + r0 + j) * DM + k], ar[j]);
        }
    }

#pragma unroll
    for (int j = 0; j < 4; ++j) {
        const float pre_i = ai[j] + b1[r0 + j];
        const float pre_r = ar[j] + b1[512 + r0 + j];
        const float inp = 1.f / (1.f + expf(-pre_i));
        const float rec = 1.f / (1.f + expf(-pre_r));
        const float sp  = log1pf(expf(Lam[r0 + j]));
        const float a   = expf(-8.f * sp * rec);
        const float c   = sqrtf(fmaxf(1.f - a * a, 0.f)) * inp;
        f2 ac; ac.x = a; ac.y = c;
        acT[(r0 + j) * S_LEN + t] = ac;
    }
}

// grid(256) x 256: block = s-pair, full t sweep. t processed in 16-step
// sections with double-buffered register x (xa/xb, all static indices).
// Steady loop has NO branches -> compiler can emit counted vmcnt; loads for
// section k+1 are issued before section k's stores, so 16-32 nt stores stay
// outstanding per wave (64-128 KB/CU in flight) instead of R4's 1.
__global__ __launch_bounds__(256) void k_rec(const float* __restrict__ x,
                                             const float* __restrict__ state0,
                                             const f2* __restrict__ acT,
                                             f4* __restrict__ out4) {
    const int bx   = blockIdx.x;         // s-pair
    const int tid  = threadIdx.x;
    const int sloc = tid >> 7;           // 0..1
    const int dq   = tid & 127;          // 0..127
    const int s    = bx * 2 + sloc;

    __shared__ f2 ac_l[2][S_LEN];        // 4 KB

    // stage a,c for both s rows (512 f2, 2 per thread)
#pragma unroll
    for (int i = 0; i < 2; ++i) {
        const int idx = i * 256 + tid;
        const int sl = idx >> 8, tt = idx & 255;
        ac_l[sl][tt] = acT[(bx * 2 + sl) * S_LEN + tt];
    }

    const f4* __restrict__ x4  = reinterpret_cast<const f4*>(x);
    const f4* __restrict__ st4 = reinterpret_cast<const f4*>(state0);
    f4 h = st4[s * 128 + dq];

    f4 xa[SEC], xb[SEC];

#define LOADSEC(BUF, SS)                                                     \
    _Pragma("unroll")                                                        \
    for (int i = 0; i < SEC; ++i)                                            \
        BUF[i] = x4[((SS) * SEC + i) * 128 + dq];

#define COMPSEC(BUF, SS)                                                     \
    _Pragma("unroll")                                                        \
    for (int i = 0; i < SEC; ++i) {                                          \
        const int t = (SS) * SEC + i;                                        \
        const f2 ac = ac_l[sloc][t];                                         \
        h.x = fmaf(ac.x, h.x, ac.y * BUF[i].x);                              \
        h.y = fmaf(ac.x, h.y, ac.y * BUF[i].y);                              \
        h.z = fmaf(ac.x, h.z, ac.y * BUF[i].z);                              \
        h.w = fmaf(ac.x, h.w, ac.y * BUF[i].w);                              \
        __builtin_nontemporal_store(h, &out4[(t * DR + s) * 128 + dq]);      \
    }

    LOADSEC(xa, 0)
    __syncthreads();                     // ac_l ready (no stores outstanding yet)

    for (int ds = 0; ds < 7; ++ds) {     // sections 0..13, branch-free body
        LOADSEC(xb, 2 * ds + 1)
        COMPSEC(xa, 2 * ds)
        LOADSEC(xa, 2 * ds + 2)
        COMPSEC(xb, 2 * ds + 1)
    }
    LOADSEC(xb, 15)                      // last loads
    COMPSEC(xa, 14)
    COMPSEC(xb, 15)

#undef LOADSEC
#undef COMPSEC

    // final state
    out4[(S_LEN * DR) * 128 + s * 128 + dq] = h;
}

extern "C" void kernel_launch(void* const* d_in, const int* in_sizes, int n_in,
                              void* d_out, int out_size, void* d_ws, size_t ws_size,
                              hipStream_t stream) {
    const float* x      = (const float*)d_in[0];
    const float* state0 = (const float*)d_in[1];
    const float* W1     = (const float*)d_in[2];
    const float* b1     = (const float*)d_in[3];
    const float* Lam    = (const float*)d_in[4];

    float* ws  = (float*)d_ws;
    float* xT  = ws;                      // 131072 floats
    f2*    acT = (f2*)(ws + 131072);      // 131072 f2

    f4* out4 = (f4*)d_out;

    k_transpose_x<<<dim3(16, 8), 256, 0, stream>>>(x, xT);
    k_gemm_act<<<dim3(128), 256, 0, stream>>>(xT, W1, b1, Lam, acT);
    k_rec<<<dim3(256), 256, 0, stream>>>(x, state0, acT, out4);
}

// Round 10
// 84.975 us; speedup vs baseline: 1.0156x; 1.0156x over previous
//
#include <hip/hip_runtime.h>
#include <hip/hip_bf16.h>

// Problem sizes (fixed by the reference)
#define S_LEN 256     // sequence length (t)
#define DM    512     // d_model (k / d)
#define DR    512     // d_rnn (s)
#define SECT  8       // t-steps per LDS section
#define NSEC  (S_LEN / SECT)   // 32

typedef float f4 __attribute__((ext_vector_type(4)));
typedef float f2 __attribute__((ext_vector_type(2)));

// ws layout (floats):
//   xT  : [512][256]     at 0       (131072)
//   acT : f2[512][256]   at 131072  (262144)

__global__ __launch_bounds__(256) void k_transpose_x(const float* __restrict__ x,
                                                     float* __restrict__ xT) {
    __shared__ float tile[32][33];
    const int k0 = blockIdx.x * 32;
    const int t0 = blockIdx.y * 32;
    const int lx = threadIdx.x & 31;
    const int ly = threadIdx.x >> 5;
#pragma unroll
    for (int i = 0; i < 32; i += 8)
        tile[ly + i][lx] = x[(t0 + ly + i) * DM + k0 + lx];
    __syncthreads();
#pragma unroll
    for (int i = 0; i < 32; i += 8)
        xT[(k0 + ly + i) * S_LEN + t0 + lx] = tile[lx][ly + i];
}

// grid(128): block g -> GEMM rows {4g..4g+3, 512+4g..512+4g+3}; epilogue writes acT.
__global__ __launch_bounds__(256) void k_gemm_act(const float* __restrict__ xT,
                                                  const float* __restrict__ W1,
                                                  const float* __restrict__ b1,
                                                  const float* __restrict__ Lam,
                                                  f2* __restrict__ acT) {
    const int g  = blockIdx.x;       // 0..127
    const int t  = threadIdx.x;      // lane axis = t (coalesced xT loads)
    const int r0 = 4 * g;

    float ai[4] = {0.f, 0.f, 0.f, 0.f};
    float ar[4] = {0.f, 0.f, 0.f, 0.f};
    const float* __restrict__ xb = xT + t;

#pragma unroll 8
    for (int k = 0; k < DM; ++k) {
        const float xv = xb[k * S_LEN];
#pragma unroll
        for (int j = 0; j < 4; ++j) {
            ai[j] = fmaf(xv, W1[(r0 + j) * DM + k], ai[j]);        // wave-uniform
            ar[j] = fmaf(xv, W1[(512 + r0 + j) * DM + k], ar[j]);
        }
    }

#pragma unroll
    for (int j = 0; j < 4; ++j) {
        const float pre_i = ai[j] + b1[r0 + j];
        const float pre_r = ar[j] + b1[512 + r0 + j];
        const float inp = 1.f / (1.f + expf(-pre_i));
        const float rec = 1.f / (1.f + expf(-pre_r));
        const float sp  = log1pf(expf(Lam[r0 + j]));
        const float a   = expf(-8.f * sp * rec);
        const float c   = sqrtf(fmaxf(1.f - a * a, 0.f)) * inp;
        f2 ac; ac.x = a; ac.y = c;
        acT[(r0 + j) * S_LEN + t] = ac;
    }
}

// grid(256) x 256: block = s-pair. KEY CHANGE vs R7: h rotates through 8 named
// registers (h0..h7), so the register sourced by a store is not overwritten
// until 8 stores later -> the compiler's store-source-WAR vmcnt wait becomes
// vmcnt(~8) instead of vmcnt(0)-per-step -> 8 nt stores in flight per wave
// (32 KB/CU). x comes from double-buffered LDS sections (lgkmcnt-only waits);
// the section prefetch's vmcnt wait lands at the ds_write with 8 stores
// younger, so stores are never drained in the loop.
__global__ __launch_bounds__(256) void k_rec(const float* __restrict__ x,
                                             const float* __restrict__ state0,
                                             const f2* __restrict__ acT,
                                             f4* __restrict__ out4) {
    const int bx   = blockIdx.x;         // s-pair
    const int tid  = threadIdx.x;
    const int sloc = tid >> 7;           // 0..1
    const int dq   = tid & 127;          // 0..127
    const int s    = bx * 2 + sloc;

    __shared__ f4 xbuf[2][SECT][128];    // 32 KB
    __shared__ f2 ac_l[2][S_LEN];        // 4 KB

    const f4* __restrict__ x4  = reinterpret_cast<const f4*>(x);
    const f4* __restrict__ st4 = reinterpret_cast<const f4*>(state0);

    // stage a,c for both s rows (512 f2, 2 per thread); covered by first barrier
#pragma unroll
    for (int i = 0; i < 2; ++i) {
        const int idx = i * 256 + tid;
        ac_l[idx >> 8][idx & 255] = acT[(bx * 2 + (idx >> 8)) * S_LEN + (idx & 255)];
    }

    f4 h0 = st4[s * 128 + dq];
    f4 h1, h2, h3, h4, h5, h6, h7;

    // section staging registers: thread covers rows {sloc, sloc+2, sloc+4, sloc+6}
    f4 xr0, xr1, xr2, xr3;

#define LOADSEC(SS) {                                                        \
        xr0 = x4[((SS) * SECT + sloc + 0) * 128 + dq];                       \
        xr1 = x4[((SS) * SECT + sloc + 2) * 128 + dq];                       \
        xr2 = x4[((SS) * SECT + sloc + 4) * 128 + dq];                       \
        xr3 = x4[((SS) * SECT + sloc + 6) * 128 + dq];                       \
    }

#define WRITESEC(B) {                                                        \
        xbuf[B][sloc + 0][dq] = xr0;                                         \
        xbuf[B][sloc + 2][dq] = xr1;                                         \
        xbuf[B][sloc + 4][dq] = xr2;                                         \
        xbuf[B][sloc + 6][dq] = xr3;                                         \
    }

#define STEP(HOLD, HNEW, B, TL, T0) {                                        \
        const f2 ac = ac_l[sloc][(T0) + (TL)];                               \
        const f4 xv = xbuf[B][TL][dq];                                       \
        HNEW.x = fmaf(ac.x, HOLD.x, ac.y * xv.x);                            \
        HNEW.y = fmaf(ac.x, HOLD.y, ac.y * xv.y);                            \
        HNEW.z = fmaf(ac.x, HOLD.z, ac.y * xv.z);                            \
        HNEW.w = fmaf(ac.x, HOLD.w, ac.y * xv.w);                            \
        __builtin_nontemporal_store(HNEW,                                    \
            &out4[(((T0) + (TL)) * DR + s) * 128 + dq]);                     \
    }

#define COMPSEC(B, T0)                                                       \
        STEP(h0, h1, B, 0, T0) STEP(h1, h2, B, 1, T0)                        \
        STEP(h2, h3, B, 2, T0) STEP(h3, h4, B, 3, T0)                        \
        STEP(h4, h5, B, 4, T0) STEP(h5, h6, B, 5, T0)                        \
        STEP(h6, h7, B, 6, T0) STEP(h7, h0, B, 7, T0)

    // prologue: section 0 into buf 0
    LOADSEC(0)
    WRITESEC(0)
    asm volatile("s_waitcnt lgkmcnt(0)" ::: "memory");
    __builtin_amdgcn_s_barrier();

    // steady loop: branch-free body; sections 0..30
    for (int ss = 0; ss < NSEC - 1; ++ss) {
        const int buf = ss & 1;
        LOADSEC(ss + 1)                      // vmcnt wait lands at WRITESEC below
        COMPSEC(buf, ss * SECT)              // 8 steps, rotating h, 8 nt stores
        WRITESEC(buf ^ 1)
        asm volatile("s_waitcnt lgkmcnt(0)" ::: "memory");
        __builtin_amdgcn_s_barrier();
    }
    // final section (31, buf 1), no prefetch
    COMPSEC(1, (NSEC - 1) * SECT)

#undef LOADSEC
#undef WRITESEC
#undef STEP
#undef COMPSEC

    // final state (value lives in h0 after 256 steps)
    out4[(S_LEN * DR) * 128 + s * 128 + dq] = h0;
}

extern "C" void kernel_launch(void* const* d_in, const int* in_sizes, int n_in,
                              void* d_out, int out_size, void* d_ws, size_t ws_size,
                              hipStream_t stream) {
    const float* x      = (const float*)d_in[0];
    const float* state0 = (const float*)d_in[1];
    const float* W1     = (const float*)d_in[2];
    const float* b1     = (const float*)d_in[3];
    const float* Lam    = (const float*)d_in[4];

    float* ws  = (float*)d_ws;
    float* xT  = ws;                      // 131072 floats
    f2*    acT = (f2*)(ws + 131072);      // 131072 f2

    f4* out4 = (f4*)d_out;

    k_transpose_x<<<dim3(16, 8), 256, 0, stream>>>(x, xT);
    k_gemm_act<<<dim3(128), 256, 0, stream>>>(xT, W1, b1, Lam, acT);
    k_rec<<<dim3(256), 256, 0, stream>>>(x, state0, acT, out4);
}

// Round 11
// 74.430 us; speedup vs baseline: 1.1594x; 1.1417x over previous
//
#include <hip/hip_runtime.h>
#include <hip/hip_bf16.h>

// Problem sizes (fixed by the reference)
#define S_LEN 256     // sequence length (t)
#define DM    512     // d_model (k / d)
#define DR    512     // d_rnn (s)

typedef float f4 __attribute__((ext_vector_type(4)));
typedef float f2 __attribute__((ext_vector_type(2)));

// ws layout (floats):
//   xT  : [512][256]     at 0       (131072)
//   acT : f2[512][256]   at 131072  (262144)

__global__ __launch_bounds__(256) void k_transpose_x(const float* __restrict__ x,
                                                     float* __restrict__ xT) {
    __shared__ float tile[32][33];
    const int k0 = blockIdx.x * 32;
    const int t0 = blockIdx.y * 32;
    const int lx = threadIdx.x & 31;
    const int ly = threadIdx.x >> 5;
#pragma unroll
    for (int i = 0; i < 32; i += 8)
        tile[ly + i][lx] = x[(t0 + ly + i) * DM + k0 + lx];
    __syncthreads();
#pragma unroll
    for (int i = 0; i < 32; i += 8)
        xT[(k0 + ly + i) * S_LEN + t0 + lx] = tile[lx][ly + i];
}

// grid(256): block g computes GEMM rows {2g, 2g+1, 512+2g, 512+2g+1} over all t,
// then applies the sigmoid/softplus/exp epilogue and writes acT[s][t] = {a, c}.
__global__ __launch_bounds__(256) void k_gemm_act(const float* __restrict__ xT,
                                                  const float* __restrict__ W1,
                                                  const float* __restrict__ b1,
                                                  const float* __restrict__ Lam,
                                                  f2* __restrict__ acT) {
    const int g  = blockIdx.x;       // 0..255
    const int t  = threadIdx.x;      // lane axis = t (coalesced xT loads)
    const int r0 = 2 * g;

    float acc0 = 0.f, acc1 = 0.f, acc2 = 0.f, acc3 = 0.f;
    const float* __restrict__ xb = xT + t;
    const float* __restrict__ w0 = W1 + (r0)       * DM;   // wave-uniform → s_loads
    const float* __restrict__ w1 = W1 + (r0 + 1)   * DM;
    const float* __restrict__ w2 = W1 + (512 + r0) * DM;
    const float* __restrict__ w3 = W1 + (513 + r0) * DM;

#pragma unroll 8
    for (int k = 0; k < DM; ++k) {
        const float xv = xb[k * S_LEN];
        acc0 = fmaf(xv, w0[k], acc0);
        acc1 = fmaf(xv, w1[k], acc1);
        acc2 = fmaf(xv, w2[k], acc2);
        acc3 = fmaf(xv, w3[k], acc3);
    }

#pragma unroll
    for (int j = 0; j < 2; ++j) {
        const float pre_i = (j ? acc1 : acc0) + b1[r0 + j];
        const float pre_r = (j ? acc3 : acc2) + b1[512 + r0 + j];
        const float inp = 1.f / (1.f + expf(-pre_i));
        const float rec = 1.f / (1.f + expf(-pre_r));
        const float sp  = log1pf(expf(Lam[r0 + j]));
        const float a   = expf(-8.f * sp * rec);
        const float c   = sqrtf(fmaxf(1.f - a * a, 0.f)) * inp;
        f2 ac; ac.x = a; ac.y = c;
        acT[(r0 + j) * S_LEN + t] = ac;
    }
}

// grid(256) x 256: identical loop to R4 (best), but the block->s-pair mapping is
// XCD-banded: XCD k (= bx%8) owns the contiguous s-band [64k, 64k+64).
// The 32 same-XCD, same-L2, same-pace blocks then emit a ~128 KB contiguous
// rolling write front per XCD instead of 4 KB fragments at 16 KB gaps,
// raising DRAM row locality of the y stream.
__global__ __launch_bounds__(256) void k_rec(const float* __restrict__ x,
                                             const float* __restrict__ state0,
                                             const f2* __restrict__ acT,
                                             f4* __restrict__ out4) {
    const int bx   = blockIdx.x;
    const int sp   = (bx & 7) * 32 + (bx >> 3);   // bijective: XCD s-banding
    const int tid  = threadIdx.x;
    const int half = tid >> 7;           // 0 or 1
    const int s    = sp * 2 + half;
    const int dq   = tid & 127;          // d/4

    __shared__ f2 ac_l[2][S_LEN];        // {a, c} per (half, t)
    f2* lf = &ac_l[0][0];
    lf[tid]       = acT[sp * 2 * S_LEN + tid];
    lf[tid + 256] = acT[sp * 2 * S_LEN + tid + 256];
    __syncthreads();

    const f4* __restrict__ st4 = reinterpret_cast<const f4*>(state0);
    f4 h = st4[s * 128 + dq];

    const f4* __restrict__ x4 = reinterpret_cast<const f4*>(x);
    f4 xv = x4[dq];                      // t = 0 prefetch

#pragma unroll 4
    for (int t = 0; t < S_LEN; ++t) {
        f4 xn;
        if (t + 1 < S_LEN) xn = x4[(t + 1) * 128 + dq];
        else xn = (f4)0.f;

        const f2 ac = ac_l[half][t];               // LDS broadcast (wave-uniform)
        const float at = ac.x, ct = ac.y;
        h.x = fmaf(at, h.x, ct * xv.x);
        h.y = fmaf(at, h.y, ct * xv.y);
        h.z = fmaf(at, h.z, ct * xv.z);
        h.w = fmaf(at, h.w, ct * xv.w);

        __builtin_nontemporal_store(h, &out4[(t * DR + s) * 128 + dq]);
        xv = xn;
    }
    // final state
    out4[(S_LEN * DR) * 128 + s * 128 + dq] = h;
}

extern "C" void kernel_launch(void* const* d_in, const int* in_sizes, int n_in,
                              void* d_out, int out_size, void* d_ws, size_t ws_size,
                              hipStream_t stream) {
    const float* x      = (const float*)d_in[0];
    const float* state0 = (const float*)d_in[1];
    const float* W1     = (const float*)d_in[2];
    const float* b1     = (const float*)d_in[3];
    const float* Lam    = (const float*)d_in[4];

    float* ws  = (float*)d_ws;
    float* xT  = ws;                      // 131072 floats
    f2*    acT = (f2*)(ws + 131072);      // 131072 f2

    f4* out4 = (f4*)d_out;

    k_transpose_x<<<dim3(16, 8), 256, 0, stream>>>(x, xT);
    k_gemm_act<<<dim3(256), 256, 0, stream>>>(xT, W1, b1, Lam, acT);
    k_rec<<<dim3(256), 256, 0, stream>>>(x, state0, acT, out4);
}